// Round 2
// baseline (265.197 us; speedup 1.0000x reference)
//
#include <hip/hip_runtime.h>
#include <math.h>

#define BB 128   // batch
#define NN 96    // perturbations
#define DD 3072  // C*H*W
#define KK 10    // classes
#define G  4     // n's per wave in k1

// ---------------- Kernel 1: logits + per-(n,b) losses ----------------
// 3072 wave-tasks: task = (n-group 0..23) * 128 + b. One wave per task,
// 4 waves per 256-thread block -> 768 blocks. Each lane covers 12 chunks
// of 4 consecutive floats (12 * 64 * 4 = 3072), W slice (4 rows x 10) in
// registers amortized over the G=4 n's. No LDS, no barriers: 40-value
// shfl_xor butterfly reduction, epilogue on lanes 0..3 (one n each).
__global__ __launch_bounds__(256) void k1_logits(
    const float* __restrict__ imgs,    // (128, 3072)
    const float* __restrict__ deltas,  // (96, 128, 3072)
    const float* __restrict__ W,       // (3072, 10)
    const float* __restrict__ bias,    // (10)
    const int*   __restrict__ labels,  // (128)
    float* __restrict__ l1_ws,         // (128, 96)
    float* __restrict__ l2_ws)         // (128, 96)
{
    const int lane = threadIdx.x & 63;
    const int task = blockIdx.x * 4 + (threadIdx.x >> 6);  // 0..3071
    const int b    = task & 127;
    const int n0   = (task >> 7) * G;

    float acc[G][KK];
#pragma unroll
    for (int j = 0; j < G; ++j)
#pragma unroll
        for (int k = 0; k < KK; ++k) acc[j][k] = 0.f;

    for (int c = 0; c < 12; ++c) {
        const int i0 = c * 256 + lane * 4;
        // W rows i0..i0+3 -> 40 consecutive floats (16B aligned)
        float w[40];
        const float4* wp = (const float4*)(W + (size_t)i0 * KK);
#pragma unroll
        for (int m = 0; m < 10; ++m) {
            float4 v = wp[m];
            w[4*m+0] = v.x; w[4*m+1] = v.y; w[4*m+2] = v.z; w[4*m+3] = v.w;
        }
        const float4 im = *(const float4*)(imgs + (size_t)b * DD + i0);
#pragma unroll
        for (int j = 0; j < G; ++j) {
            const int n = n0 + j;
            const float4 dl = *(const float4*)(deltas + ((size_t)(n * BB + b)) * DD + i0);
            const float x0 = fminf(fmaxf(im.x + dl.x, 0.f), 1.f);
            const float x1 = fminf(fmaxf(im.y + dl.y, 0.f), 1.f);
            const float x2 = fminf(fmaxf(im.z + dl.z, 0.f), 1.f);
            const float x3 = fminf(fmaxf(im.w + dl.w, 0.f), 1.f);
#pragma unroll
            for (int k = 0; k < KK; ++k) {
                acc[j][k] = fmaf(x3, w[30+k],
                            fmaf(x2, w[20+k],
                            fmaf(x1, w[10+k],
                            fmaf(x0, w[k], acc[j][k]))));
            }
        }
    }

    // Wave butterfly: after 6 xor steps every lane holds all 40 totals.
#pragma unroll
    for (int j = 0; j < G; ++j)
#pragma unroll
        for (int k = 0; k < KK; ++k) {
            float s = acc[j][k];
#pragma unroll
            for (int off = 1; off < 64; off <<= 1)
                s += __shfl_xor(s, off, 64);
            acc[j][k] = s;
        }

    if (lane < G) {
        float lg[KK];
#pragma unroll
        for (int k = 0; k < KK; ++k) {
            float v = acc[0][k];
            if (lane == 1) v = acc[1][k];
            if (lane == 2) v = acc[2][k];
            if (lane == 3) v = acc[3][k];
            lg[k] = v + bias[k];
        }
        const int n = n0 + lane;
        // top-1 (first max -> lower index on ties, matches lax.top_k)
        int top1 = 0; float m1 = lg[0];
#pragma unroll
        for (int k = 1; k < KK; ++k) if (lg[k] > m1) { m1 = lg[k]; top1 = k; }
        // second (first max among k != top1)
        int sec = (top1 == 0) ? 1 : 0; float m2 = lg[sec];
#pragma unroll
        for (int k = 0; k < KK; ++k)
            if (k != top1 && lg[k] > m2) { m2 = lg[k]; sec = k; }
        // log-sum-exp (max-stabilized, like jax log_softmax)
        float se = 0.f;
#pragma unroll
        for (int k = 0; k < KK; ++k) se += expf(lg[k] - m1);
        const float lse = m1 + logf(se);
        const int lab = labels[b];
        const float loss1 = lse - lg[lab];
        const float loss2 = (top1 == lab) ? (lse - lg[sec]) : -10000.0f;
        l1_ws[b * NN + n] = loss1;
        l2_ws[b * NN + n] = loss2;
    }
}

// ---------------- Kernel 2: per-b stable rank-ind selection ----------------
__global__ __launch_bounds__(128) void k2_select(
    const float* __restrict__ l1_ws, const float* __restrict__ l2_ws,
    const int* __restrict__ ind_p, float* __restrict__ perb)
{
    const int b = blockIdx.x;
    const int t = threadIdx.x;
    __shared__ float sd[NN];
    __shared__ float sl2[NN];
    __shared__ float ssel;
    __shared__ float swsum[2];

    float myl1 = 0.f, myd = 0.f;
    if (t < NN) {
        const float a = l1_ws[b * NN + t];
        const float c = l2_ws[b * NN + t];
        myl1 = a; myd = a - c;
        sd[t] = myd; sl2[t] = c;
    }
    __syncthreads();

    if (t < NN) {
        int rank = 0;
        for (int j = 0; j < NN; ++j) {
            const float dj = sd[j];
            rank += (dj < myd) || (dj == myd && j < t);  // stable argsort
        }
        if (rank == ind_p[0]) ssel = sl2[t];
    }

    float s = myl1;
#pragma unroll
    for (int off = 32; off >= 1; off >>= 1) s += __shfl_down(s, off, 64);
    if ((t & 63) == 0) swsum[t >> 6] = s;
    __syncthreads();
    if (t == 0) {
        const float total = swsum[0] + swsum[1];
        perb[b] = total / 96.0f - ssel;
    }
}

// ---------------- Kernel 3: final mean over b ----------------
__global__ __launch_bounds__(128) void k3_final(
    const float* __restrict__ perb, float* __restrict__ out)
{
    const int t = threadIdx.x;
    float s = perb[t];
#pragma unroll
    for (int off = 32; off >= 1; off >>= 1) s += __shfl_down(s, off, 64);
    __shared__ float sw[2];
    if ((t & 63) == 0) sw[t >> 6] = s;
    __syncthreads();
    if (t == 0) out[0] = (sw[0] + sw[1]) / 128.0f;
}

extern "C" void kernel_launch(void* const* d_in, const int* in_sizes, int n_in,
                              void* d_out, int out_size, void* d_ws, size_t ws_size,
                              hipStream_t stream) {
    const float* imgs   = (const float*)d_in[0];
    const float* deltas = (const float*)d_in[1];
    const float* W      = (const float*)d_in[2];
    const float* bias   = (const float*)d_in[3];
    const int*   labels = (const int*)d_in[4];
    const int*   ind    = (const int*)d_in[5];
    float* out = (float*)d_out;

    float* l1_ws = (float*)d_ws;             // 12288 floats
    float* l2_ws = l1_ws + NN * BB;          // 12288 floats
    float* perb  = l2_ws + NN * BB;          // 128 floats

    k1_logits<<<dim3(768), dim3(256), 0, stream>>>(
        imgs, deltas, W, bias, labels, l1_ws, l2_ws);
    k2_select<<<dim3(BB), dim3(128), 0, stream>>>(l1_ws, l2_ws, ind, perb);
    k3_final<<<dim3(1), dim3(128), 0, stream>>>(perb, out);
}